// Round 1
// baseline (17566.148 us; speedup 1.0000x reference)
//
#include <hip/hip_runtime.h>
#include <math.h>

#define D 4096
#define NB 128
#define TSY 128
#define KC 32
#define NTILES (D / TSY)

__device__ __forceinline__ float softplusf(float x) {
  return fmaxf(x, 0.0f) + log1pf(expf(-fabsf(x)));
}

// mode 0: Mout[gi*D+gj] = acc + (gi==gj ? softplus(n[gi]) : 0)   (Asrc=A, K=4096)
// mode 1: Mout[gi*D+gj] -= acc                                   (Asrc=panel, K=128)
// Only lower tiles (ti>=tj) are launched; diagonal tiles written in full (symmetric).
__global__ __launch_bounds__(256) void syrk_kernel(
    const float* __restrict__ Asrc, int K, const float* __restrict__ nvec,
    float* __restrict__ Mout, int mode)
{
  __shared__ float As[KC][TSY + 4];
  __shared__ float Bs[KC][TSY + 4];
  int b = blockIdx.x;
  int ti = (int)((sqrtf(8.0f * (float)b + 1.0f) - 1.0f) * 0.5f);
  while ((ti + 1) * (ti + 2) / 2 <= b) ++ti;
  while (ti * (ti + 1) / 2 > b) --ti;
  int tj = b - ti * (ti + 1) / 2;
  int row0 = ti * TSY, col0 = tj * TSY;
  int tid = threadIdx.x;
  int tx = tid & 15, ty = tid >> 4;

  float acc[8][8];
#pragma unroll
  for (int r = 0; r < 8; ++r)
#pragma unroll
    for (int c = 0; c < 8; ++c) acc[r][c] = 0.0f;

  int lr = tid >> 1;            // row within tile (0..127)
  int lc0 = (tid & 1) * 16;     // 16-wide col chunk within KC=32

  for (int kk = 0; kk < K; kk += KC) {
    const float* pa = Asrc + (size_t)(row0 + lr) * D + (kk + lc0);
    const float* pb = Asrc + (size_t)(col0 + lr) * D + (kk + lc0);
    float4 av[4], bv[4];
#pragma unroll
    for (int q = 0; q < 4; ++q) {
      av[q] = *(const float4*)(pa + 4 * q);
      bv[q] = *(const float4*)(pb + 4 * q);
    }
    __syncthreads();   // previous chunk's compute done before LDS overwrite
#pragma unroll
    for (int q = 0; q < 4; ++q) {
      As[lc0 + 4*q + 0][lr] = av[q].x;
      As[lc0 + 4*q + 1][lr] = av[q].y;
      As[lc0 + 4*q + 2][lr] = av[q].z;
      As[lc0 + 4*q + 3][lr] = av[q].w;
      Bs[lc0 + 4*q + 0][lr] = bv[q].x;
      Bs[lc0 + 4*q + 1][lr] = bv[q].y;
      Bs[lc0 + 4*q + 2][lr] = bv[q].z;
      Bs[lc0 + 4*q + 3][lr] = bv[q].w;
    }
    __syncthreads();
#pragma unroll
    for (int p = 0; p < KC; ++p) {
      float4 a0 = *(const float4*)&As[p][ty * 8];
      float4 a1 = *(const float4*)&As[p][ty * 8 + 4];
      float4 b0 = *(const float4*)&Bs[p][tx * 8];
      float4 b1 = *(const float4*)&Bs[p][tx * 8 + 4];
      float ar[8] = {a0.x, a0.y, a0.z, a0.w, a1.x, a1.y, a1.z, a1.w};
      float br[8] = {b0.x, b0.y, b0.z, b0.w, b1.x, b1.y, b1.z, b1.w};
#pragma unroll
      for (int r = 0; r < 8; ++r)
#pragma unroll
        for (int c = 0; c < 8; ++c) acc[r][c] += ar[r] * br[c];
    }
  }

#pragma unroll
  for (int r = 0; r < 8; ++r) {
    int gi = row0 + ty * 8 + r;
    float* mrow = Mout + (size_t)gi * D + col0 + tx * 8;
    if (mode == 0) {
      int gj0 = col0 + tx * 8;
#pragma unroll
      for (int c = 0; c < 8; ++c) {
        float v = acc[r][c];
        if (gi == gj0 + c) v += softplusf(nvec[gi]);
        mrow[c] = v;
      }
    } else {
      float4 m0 = *(const float4*)mrow;
      float4 m1 = *(const float4*)(mrow + 4);
      m0.x -= acc[r][0]; m0.y -= acc[r][1]; m0.z -= acc[r][2]; m0.w -= acc[r][3];
      m1.x -= acc[r][4]; m1.y -= acc[r][5]; m1.z -= acc[r][6]; m1.w -= acc[r][7];
      *(float4*)mrow = m0;
      *(float4*)(mrow + 4) = m1;
    }
  }
}

// Single-block in-LDS Cholesky of the 128x128 diagonal block at (kb,kb).
__global__ __launch_bounds__(256) void potrf_kernel(float* __restrict__ M, int kb)
{
  __shared__ float Ls[NB][NB + 1];
  int tid = threadIdx.x;
  float* Msrc = M + (size_t)kb * D + kb;
  for (int idx = tid; idx < NB * NB; idx += 256) {
    int i = idx >> 7, j = idx & (NB - 1);
    Ls[i][j] = (j <= i) ? Msrc[(size_t)i * D + j] : 0.0f;
  }
  __syncthreads();
  for (int j = 0; j < NB; ++j) {
    float d = Ls[j][j];
    float s = 1.0f / sqrtf(d);
    __syncthreads();                       // all threads have read d
    for (int i = j + tid; i < NB; i += 256) Ls[i][j] *= s;   // i=j -> sqrt(d)
    __syncthreads();                       // column j final
    for (int i = j + 1 + tid; i < NB; i += 256) {
      float lij = Ls[i][j];
      for (int c = j + 1; c <= i; ++c) Ls[i][c] -= lij * Ls[c][j];
    }
    __syncthreads();                       // trailing ready for next j
  }
  for (int idx = tid; idx < NB * NB; idx += 256) {
    int i = idx >> 7, j = idx & (NB - 1);
    if (j <= i) Msrc[(size_t)i * D + j] = Ls[i][j];
  }
}

// Panel solve: rows [kb+NB, D) of cols [kb, kb+NB): X * L11^T = M21.
// One wave handles 2 rows; each lane holds x[lane], x[64+lane] per row in regs.
__global__ __launch_bounds__(256) void trsm_kernel(float* __restrict__ M, int kb)
{
  __shared__ float Ls[NB][NB + 1];
  __shared__ float dinv[NB];
  int tid = threadIdx.x;
  const float* Lsrc = M + (size_t)kb * D + kb;
  for (int idx = tid; idx < NB * NB; idx += 256) {
    int i = idx >> 7, j = idx & (NB - 1);
    Ls[i][j] = (j <= i) ? Lsrc[(size_t)i * D + j] : 0.0f;
  }
  __syncthreads();
  if (tid < NB) dinv[tid] = 1.0f / Ls[tid][tid];
  __syncthreads();
  int lane = tid & 63, w = tid >> 6;
  size_t r0 = (size_t)(kb + NB) + (size_t)blockIdx.x * 8 + w * 2;
  float* p0 = M + r0 * D + kb;
  float* p1 = p0 + D;
  float x0l = p0[lane], x0h = p0[64 + lane];
  float x1l = p1[lane], x1h = p1[64 + lane];
  for (int p = 0; p < 64; ++p) {
    float dv = dinv[p];
    float xp0 = __shfl(x0l, p) * dv;
    float xp1 = __shfl(x1l, p) * dv;
    float Llo = Ls[lane][p];
    float Lhi = Ls[64 + lane][p];
    if (lane == p)      { x0l = xp0; x1l = xp1; }
    else if (lane > p)  { x0l -= xp0 * Llo; x1l -= xp1 * Llo; }
    x0h -= xp0 * Lhi;
    x1h -= xp1 * Lhi;
  }
  for (int p = 64; p < NB; ++p) {
    int q = p - 64;
    float dv = dinv[p];
    float xp0 = __shfl(x0h, q) * dv;
    float xp1 = __shfl(x1h, q) * dv;
    float Lhi = Ls[64 + lane][p];
    if (lane == q)      { x0h = xp0; x1h = xp1; }
    else if (lane > q)  { x0h -= xp0 * Lhi; x1h -= xp1 * Lhi; }
  }
  p0[lane] = x0l; p0[64 + lane] = x0h;
  p1[lane] = x1l; p1[64 + lane] = x1h;
}

__global__ __launch_bounds__(256) void zero_upper_kernel(float* __restrict__ M)
{
  size_t idx = (size_t)blockIdx.x * 256 + threadIdx.x;
  int i = (int)(idx >> 12);
  int j = (int)(idx & (D - 1));
  if (j > i) M[idx] = 0.0f;
}

extern "C" void kernel_launch(void* const* d_in, const int* in_sizes, int n_in,
                              void* d_out, int out_size, void* d_ws, size_t ws_size,
                              hipStream_t stream)
{
  (void)in_sizes; (void)n_in; (void)d_ws; (void)ws_size; (void)out_size;
  const float* A  = (const float*)d_in[0];
  const float* nv = (const float*)d_in[1];
  float* M = (float*)d_out;

  // M = A*A^T + diag(softplus(n)), lower tiles (diag tiles full)
  syrk_kernel<<<NTILES * (NTILES + 1) / 2, 256, 0, stream>>>(A, D, nv, M, 0);

  for (int k = 0; k < D / NB; ++k) {
    int kb = k * NB;
    potrf_kernel<<<1, 256, 0, stream>>>(M, kb);
    int T = D - kb - NB;
    if (T > 0) {
      trsm_kernel<<<T / 8, 256, 0, stream>>>(M, kb);
      int t = T / TSY;
      syrk_kernel<<<t * (t + 1) / 2, 256, 0, stream>>>(
          M + (size_t)(kb + NB) * D + kb, NB, nullptr,
          M + (size_t)(kb + NB) * D + (kb + NB), 1);
    }
  }

  zero_upper_kernel<<<(int)(((size_t)D * D) / 256), 256, 0, stream>>>(M);
}

// Round 2
// 5488.745 us; speedup vs baseline: 3.2004x; 3.2004x over previous
//
#include <hip/hip_runtime.h>
#include <math.h>

#define D 4096
#define NB 128
#define TSY 128
#define KC 32
#define NTILES (D / TSY)

__device__ __forceinline__ float softplusf(float x) {
  return fmaxf(x, 0.0f) + log1pf(expf(-fabsf(x)));
}

// mode 0: Mout[gi*D+gj] = acc + (gi==gj ? softplus(n[gi]) : 0)   (Asrc=A, K=4096)
// mode 1: Mout[gi*D+gj] -= acc                                   (Asrc=panel, K=128)
// Only lower tiles (ti>=tj) are launched; diagonal tiles written in full (symmetric).
__global__ __launch_bounds__(256) void syrk_kernel(
    const float* __restrict__ Asrc, int K, const float* __restrict__ nvec,
    float* __restrict__ Mout, int mode)
{
  __shared__ float As[KC][TSY + 4];
  __shared__ float Bs[KC][TSY + 4];
  int b = blockIdx.x;
  int ti = (int)((sqrtf(8.0f * (float)b + 1.0f) - 1.0f) * 0.5f);
  while ((ti + 1) * (ti + 2) / 2 <= b) ++ti;
  while (ti * (ti + 1) / 2 > b) --ti;
  int tj = b - ti * (ti + 1) / 2;
  int row0 = ti * TSY, col0 = tj * TSY;
  int tid = threadIdx.x;
  int tx = tid & 15, ty = tid >> 4;

  float acc[8][8];
#pragma unroll
  for (int r = 0; r < 8; ++r)
#pragma unroll
    for (int c = 0; c < 8; ++c) acc[r][c] = 0.0f;

  int lr = tid >> 1;            // row within tile (0..127)
  int lc0 = (tid & 1) * 16;     // 16-wide col chunk within KC=32

  for (int kk = 0; kk < K; kk += KC) {
    const float* pa = Asrc + (size_t)(row0 + lr) * D + (kk + lc0);
    const float* pb = Asrc + (size_t)(col0 + lr) * D + (kk + lc0);
    float4 av[4], bv[4];
#pragma unroll
    for (int q = 0; q < 4; ++q) {
      av[q] = *(const float4*)(pa + 4 * q);
      bv[q] = *(const float4*)(pb + 4 * q);
    }
    __syncthreads();   // previous chunk's compute done before LDS overwrite
#pragma unroll
    for (int q = 0; q < 4; ++q) {
      As[lc0 + 4*q + 0][lr] = av[q].x;
      As[lc0 + 4*q + 1][lr] = av[q].y;
      As[lc0 + 4*q + 2][lr] = av[q].z;
      As[lc0 + 4*q + 3][lr] = av[q].w;
      Bs[lc0 + 4*q + 0][lr] = bv[q].x;
      Bs[lc0 + 4*q + 1][lr] = bv[q].y;
      Bs[lc0 + 4*q + 2][lr] = bv[q].z;
      Bs[lc0 + 4*q + 3][lr] = bv[q].w;
    }
    __syncthreads();
#pragma unroll
    for (int p = 0; p < KC; ++p) {
      float4 a0 = *(const float4*)&As[p][ty * 8];
      float4 a1 = *(const float4*)&As[p][ty * 8 + 4];
      float4 b0 = *(const float4*)&Bs[p][tx * 8];
      float4 b1 = *(const float4*)&Bs[p][tx * 8 + 4];
      float ar[8] = {a0.x, a0.y, a0.z, a0.w, a1.x, a1.y, a1.z, a1.w};
      float br[8] = {b0.x, b0.y, b0.z, b0.w, b1.x, b1.y, b1.z, b1.w};
#pragma unroll
      for (int r = 0; r < 8; ++r)
#pragma unroll
        for (int c = 0; c < 8; ++c) acc[r][c] += ar[r] * br[c];
    }
  }

#pragma unroll
  for (int r = 0; r < 8; ++r) {
    int gi = row0 + ty * 8 + r;
    float* mrow = Mout + (size_t)gi * D + col0 + tx * 8;
    if (mode == 0) {
      int gj0 = col0 + tx * 8;
#pragma unroll
      for (int c = 0; c < 8; ++c) {
        float v = acc[r][c];
        if (gi == gj0 + c) v += softplusf(nvec[gi]);
        mrow[c] = v;
      }
    } else {
      float4 m0 = *(const float4*)mrow;
      float4 m1 = *(const float4*)(mrow + 4);
      m0.x -= acc[r][0]; m0.y -= acc[r][1]; m0.z -= acc[r][2]; m0.w -= acc[r][3];
      m1.x -= acc[r][4]; m1.y -= acc[r][5]; m1.z -= acc[r][6]; m1.w -= acc[r][7];
      *(float4*)mrow = m0;
      *(float4*)(mrow + 4) = m1;
    }
  }
}

// Single-block in-LDS Cholesky of the 128x128 diagonal block at (kb,kb).
// Two-level blocked: 8 mini-panels of 16 columns. Panel columns are factored
// with 128 row-owner threads holding the panel row in REGISTERS (no LDS RMW
// chain); the rank-16 trailing update is a register-tiled 8x8 GEMM in LDS.
__global__ __launch_bounds__(256) void potrf_kernel(float* __restrict__ M, int kb)
{
  __shared__ float Ls[NB][NB + 1];
  __shared__ float colbuf[16][NB];
  __shared__ float shd[16];
  int tid = threadIdx.x;
  float* Msrc = M + (size_t)kb * D + kb;
  for (int idx = tid; idx < NB * NB; idx += 256) {
    int i = idx >> 7, j = idx & (NB - 1);
    Ls[i][j] = (j <= i) ? Msrc[(size_t)i * D + j] : 0.0f;
  }
  __syncthreads();

  int t = tid;                   // row owner for t < 128
  int tx = tid & 15, ty = tid >> 4;

  for (int pp = 0; pp < 8; ++pp) {
    int pc0 = pp * 16;
    // load panel row into registers
    float x[16];
#pragma unroll
    for (int c = 0; c < 16; ++c)
      x[c] = (t < NB && t >= pc0) ? Ls[t][pc0 + c] : 0.0f;

    // factor 16 columns; j fully unrolled so x[] stays in registers
#pragma unroll
    for (int j = 0; j < 16; ++j) {
      int jj = pc0 + j;
      if (t == jj) shd[j] = x[j];
      __syncthreads();
      float s = 1.0f / sqrtf(shd[j]);
      float l = x[j] * s;
      if (t < NB && t >= jj) { colbuf[j][t] = l; x[j] = l; }
      __syncthreads();
      if (t < NB && t > jj) {
#pragma unroll
        for (int c = 0; c < 16; ++c)
          if (c > j) x[c] -= l * colbuf[j][pc0 + c];
      }
    }
    __syncthreads();             // all colbuf reads done before Ls writeback
    if (t < NB && t >= pc0) {
#pragma unroll
      for (int c = 0; c < 16; ++c) Ls[t][pc0 + c] = x[c];
    }
    __syncthreads();             // panel visible in LDS

    // rank-16 trailing update: Ls[r][c] -= sum_q Ls[r][pc0+q]*Ls[c][pc0+q]
    int s0 = pc0 + 16;
    if (s0 < NB) {
      int r0 = ty * 8, c0 = tx * 8;
      if (r0 >= s0 && c0 >= s0) {
        float acc[8][8];
#pragma unroll
        for (int rr = 0; rr < 8; ++rr) {
          float4 m0 = *(const float4*)&Ls[r0 + rr][c0];
          float4 m1 = *(const float4*)&Ls[r0 + rr][c0 + 4];
          acc[rr][0] = m0.x; acc[rr][1] = m0.y; acc[rr][2] = m0.z; acc[rr][3] = m0.w;
          acc[rr][4] = m1.x; acc[rr][5] = m1.y; acc[rr][6] = m1.z; acc[rr][7] = m1.w;
        }
#pragma unroll
        for (int q = 0; q < 16; ++q) {
          float av[8], bv[8];
#pragma unroll
          for (int rr = 0; rr < 8; ++rr) av[rr] = Ls[r0 + rr][pc0 + q];
#pragma unroll
          for (int cc = 0; cc < 8; ++cc) bv[cc] = Ls[c0 + cc][pc0 + q];
#pragma unroll
          for (int rr = 0; rr < 8; ++rr)
#pragma unroll
            for (int cc = 0; cc < 8; ++cc) acc[rr][cc] -= av[rr] * bv[cc];
        }
#pragma unroll
        for (int rr = 0; rr < 8; ++rr) {
          *(float4*)&Ls[r0 + rr][c0] =
              make_float4(acc[rr][0], acc[rr][1], acc[rr][2], acc[rr][3]);
          *(float4*)&Ls[r0 + rr][c0 + 4] =
              make_float4(acc[rr][4], acc[rr][5], acc[rr][6], acc[rr][7]);
        }
      }
    }
    __syncthreads();             // update done before next panel's reg load
  }

  for (int idx = tid; idx < NB * NB; idx += 256) {
    int i = idx >> 7, j = idx & (NB - 1);
    if (j <= i) Msrc[(size_t)i * D + j] = Ls[i][j];
  }
}

// Panel solve: rows [kb+NB, D) of cols [kb, kb+NB): X * L11^T = M21.
// One wave handles 2 rows; each lane holds x[lane], x[64+lane] per row in regs.
__global__ __launch_bounds__(256) void trsm_kernel(float* __restrict__ M, int kb)
{
  __shared__ float Ls[NB][NB + 1];
  __shared__ float dinv[NB];
  int tid = threadIdx.x;
  const float* Lsrc = M + (size_t)kb * D + kb;
  for (int idx = tid; idx < NB * NB; idx += 256) {
    int i = idx >> 7, j = idx & (NB - 1);
    Ls[i][j] = (j <= i) ? Lsrc[(size_t)i * D + j] : 0.0f;
  }
  __syncthreads();
  if (tid < NB) dinv[tid] = 1.0f / Ls[tid][tid];
  __syncthreads();
  int lane = tid & 63, w = tid >> 6;
  size_t r0 = (size_t)(kb + NB) + (size_t)blockIdx.x * 8 + w * 2;
  float* p0 = M + r0 * D + kb;
  float* p1 = p0 + D;
  float x0l = p0[lane], x0h = p0[64 + lane];
  float x1l = p1[lane], x1h = p1[64 + lane];
  for (int p = 0; p < 64; ++p) {
    float dv = dinv[p];
    float xp0 = __shfl(x0l, p) * dv;
    float xp1 = __shfl(x1l, p) * dv;
    float Llo = Ls[lane][p];
    float Lhi = Ls[64 + lane][p];
    if (lane == p)      { x0l = xp0; x1l = xp1; }
    else if (lane > p)  { x0l -= xp0 * Llo; x1l -= xp1 * Llo; }
    x0h -= xp0 * Lhi;
    x1h -= xp1 * Lhi;
  }
  for (int p = 64; p < NB; ++p) {
    int q = p - 64;
    float dv = dinv[p];
    float xp0 = __shfl(x0h, q) * dv;
    float xp1 = __shfl(x1h, q) * dv;
    float Lhi = Ls[64 + lane][p];
    if (lane == q)      { x0h = xp0; x1h = xp1; }
    else if (lane > q)  { x0h -= xp0 * Lhi; x1h -= xp1 * Lhi; }
  }
  p0[lane] = x0l; p0[64 + lane] = x0h;
  p1[lane] = x1l; p1[64 + lane] = x1h;
}

__global__ __launch_bounds__(256) void zero_upper_kernel(float* __restrict__ M)
{
  size_t idx = (size_t)blockIdx.x * 256 + threadIdx.x;
  int i = (int)(idx >> 12);
  int j = (int)(idx & (D - 1));
  if (j > i) M[idx] = 0.0f;
}

extern "C" void kernel_launch(void* const* d_in, const int* in_sizes, int n_in,
                              void* d_out, int out_size, void* d_ws, size_t ws_size,
                              hipStream_t stream)
{
  (void)in_sizes; (void)n_in; (void)d_ws; (void)ws_size; (void)out_size;
  const float* A  = (const float*)d_in[0];
  const float* nv = (const float*)d_in[1];
  float* M = (float*)d_out;

  // M = A*A^T + diag(softplus(n)), lower tiles (diag tiles full)
  syrk_kernel<<<NTILES * (NTILES + 1) / 2, 256, 0, stream>>>(A, D, nv, M, 0);

  for (int k = 0; k < D / NB; ++k) {
    int kb = k * NB;
    potrf_kernel<<<1, 256, 0, stream>>>(M, kb);
    int T = D - kb - NB;
    if (T > 0) {
      trsm_kernel<<<T / 8, 256, 0, stream>>>(M, kb);
      int t = T / TSY;
      syrk_kernel<<<t * (t + 1) / 2, 256, 0, stream>>>(
          M + (size_t)(kb + NB) * D + kb, NB, nullptr,
          M + (size_t)(kb + NB) * D + (kb + NB), 1);
    }
  }

  zero_upper_kernel<<<(int)(((size_t)D * D) / 256), 256, 0, stream>>>(M);
}

// Round 4
// 4682.871 us; speedup vs baseline: 3.7511x; 1.1721x over previous
//
#include <hip/hip_runtime.h>
#include <math.h>

#define D 4096
#define NB 128
#define TSY 128
#define KC 32
#define NTILES (D / TSY)
#define LDP 40   // padded LDS row stride in bf16 elems (80 B)

typedef __attribute__((ext_vector_type(8))) short short8;
typedef __attribute__((ext_vector_type(4))) float f32x4;
typedef __attribute__((ext_vector_type(4))) unsigned int uint4v;

__device__ __forceinline__ float softplusf(float x) {
  return fmaxf(x, 0.0f) + log1pf(expf(-fabsf(x)));
}

struct HL { unsigned int h, l; };

// split two fp32 into packed bf16 hi (truncated) and bf16 lo (residual, truncated)
__device__ __forceinline__ HL split2(float x0, float x1) {
  unsigned int b0 = __float_as_uint(x0), b1 = __float_as_uint(x1);
  unsigned int h0 = b0 & 0xFFFF0000u, h1 = b1 & 0xFFFF0000u;
  float r0 = x0 - __uint_as_float(h0);
  float r1 = x1 - __uint_as_float(h1);
  HL out;
  out.h = h1 | (h0 >> 16);
  out.l = (__float_as_uint(r1) & 0xFFFF0000u) | (__float_as_uint(r0) >> 16);
  return out;
}

// C[128x128 tile] = Arows · Brows^T via split-bf16 MFMA.
// mode 0: Mout = acc (+ softplus diag), K=4096.  mode 1: Mout -= acc, K=128.
// Only lower tiles launched (ti>=tj); diagonal tiles computed in full.
__global__ __launch_bounds__(256) void syrk_kernel(
    const float* __restrict__ Asrc, int K, const float* __restrict__ nvec,
    float* __restrict__ Mout, int mode)
{
  __shared__ unsigned short Ah[TSY][LDP], Al[TSY][LDP];
  __shared__ unsigned short Bh[TSY][LDP], Bl[TSY][LDP];

  int b = blockIdx.x;
  int ti = (int)((sqrtf(8.0f * (float)b + 1.0f) - 1.0f) * 0.5f);
  while ((ti + 1) * (ti + 2) / 2 <= b) ++ti;
  while (ti * (ti + 1) / 2 > b) --ti;
  int tj = b - ti * (ti + 1) / 2;
  int row0 = ti * TSY, col0 = tj * TSY;

  int tid = threadIdx.x;
  int lane = tid & 63, wid = tid >> 6;
  int wr = wid >> 1, wc = wid & 1;          // wave's 64x64 quadrant
  int srow = tid >> 1;                      // staging: row this thread loads
  int scg = (tid & 1) * 16;                 // staging: k-offset (0 or 16)

  f32x4 acc[4][4];
#pragma unroll
  for (int m = 0; m < 4; ++m)
#pragma unroll
    for (int n = 0; n < 4; ++n) acc[m][n] = (f32x4){0.f, 0.f, 0.f, 0.f};

  int lr16 = lane & 15, kof = (lane >> 4) * 8;

  for (int kk = 0; kk < K; kk += KC) {
    const float* pa = Asrc + (size_t)(row0 + srow) * D + kk + scg;
    const float* pb = Asrc + (size_t)(col0 + srow) * D + kk + scg;
    float4 av0 = *(const float4*)(pa + 0), av1 = *(const float4*)(pa + 4);
    float4 av2 = *(const float4*)(pa + 8), av3 = *(const float4*)(pa + 12);
    float4 bv0 = *(const float4*)(pb + 0), bv1 = *(const float4*)(pb + 4);
    float4 bv2 = *(const float4*)(pb + 8), bv3 = *(const float4*)(pb + 12);

    __syncthreads();   // previous chunk's MFMA reads done before LDS overwrite

    {
      HL p0 = split2(av0.x, av0.y), p1 = split2(av0.z, av0.w);
      HL p2 = split2(av1.x, av1.y), p3 = split2(av1.z, av1.w);
      HL p4 = split2(av2.x, av2.y), p5 = split2(av2.z, av2.w);
      HL p6 = split2(av3.x, av3.y), p7 = split2(av3.z, av3.w);
      uint4v h0 = {p0.h, p1.h, p2.h, p3.h}, l0 = {p0.l, p1.l, p2.l, p3.l};
      uint4v h1 = {p4.h, p5.h, p6.h, p7.h}, l1 = {p4.l, p5.l, p6.l, p7.l};
      *(uint4v*)&Ah[srow][scg] = h0;  *(uint4v*)&Ah[srow][scg + 8] = h1;
      *(uint4v*)&Al[srow][scg] = l0;  *(uint4v*)&Al[srow][scg + 8] = l1;
    }
    {
      HL p0 = split2(bv0.x, bv0.y), p1 = split2(bv0.z, bv0.w);
      HL p2 = split2(bv1.x, bv1.y), p3 = split2(bv1.z, bv1.w);
      HL p4 = split2(bv2.x, bv2.y), p5 = split2(bv2.z, bv2.w);
      HL p6 = split2(bv3.x, bv3.y), p7 = split2(bv3.z, bv3.w);
      uint4v h0 = {p0.h, p1.h, p2.h, p3.h}, l0 = {p0.l, p1.l, p2.l, p3.l};
      uint4v h1 = {p4.h, p5.h, p6.h, p7.h}, l1 = {p4.l, p5.l, p6.l, p7.l};
      *(uint4v*)&Bh[srow][scg] = h0;  *(uint4v*)&Bh[srow][scg + 8] = h1;
      *(uint4v*)&Bl[srow][scg] = l0;  *(uint4v*)&Bl[srow][scg + 8] = l1;
    }

    __syncthreads();

    short8 ah[4], al[4], bh[4], bl[4];
#pragma unroll
    for (int m = 0; m < 4; ++m) {
      int r = wr * 64 + m * 16 + lr16;
      ah[m] = *(const short8*)&Ah[r][kof];
      al[m] = *(const short8*)&Al[r][kof];
    }
#pragma unroll
    for (int n = 0; n < 4; ++n) {
      int c = wc * 64 + n * 16 + lr16;
      bh[n] = *(const short8*)&Bh[c][kof];
      bl[n] = *(const short8*)&Bl[c][kof];
    }
#pragma unroll
    for (int m = 0; m < 4; ++m)
#pragma unroll
      for (int n = 0; n < 4; ++n) {
        acc[m][n] = __builtin_amdgcn_mfma_f32_16x16x32_bf16(ah[m], bh[n], acc[m][n], 0, 0, 0);
        acc[m][n] = __builtin_amdgcn_mfma_f32_16x16x32_bf16(ah[m], bl[n], acc[m][n], 0, 0, 0);
        acc[m][n] = __builtin_amdgcn_mfma_f32_16x16x32_bf16(al[m], bh[n], acc[m][n], 0, 0, 0);
      }
  }

  // epilogue: C/D layout col = lane&15, row = (lane>>4)*4 + reg
  int cl = lane & 15, rg = (lane >> 4) * 4;
#pragma unroll
  for (int m = 0; m < 4; ++m) {
#pragma unroll
    for (int n = 0; n < 4; ++n) {
      int gi0 = row0 + wr * 64 + m * 16 + rg;
      int gj = col0 + wc * 64 + n * 16 + cl;
      if (mode == 0) {
#pragma unroll
        for (int r = 0; r < 4; ++r) {
          int gi = gi0 + r;
          float v = acc[m][n][r];
          if (gi == gj) v += softplusf(nvec[gi]);
          Mout[(size_t)gi * D + gj] = v;
        }
      } else {
#pragma unroll
        for (int r = 0; r < 4; ++r) {
          int gi = gi0 + r;
          Mout[(size_t)gi * D + gj] -= acc[m][n][r];
        }
      }
    }
  }
}

// Single-block in-LDS Cholesky of the 128x128 diagonal block at (kb,kb).
// Panel (16 cols) factored wave-synchronously by wave 0 (2 rows/lane in regs,
// shfl broadcasts, no barriers); rank-16 trailing update by all 4 waves.
__global__ __launch_bounds__(256) void potrf_kernel(float* __restrict__ M, int kb)
{
  __shared__ float Ls[NB][NB + 1];
  int tid = threadIdx.x;
  float* Msrc = M + (size_t)kb * D + kb;
  for (int idx = tid; idx < NB * NB; idx += 256) {
    int i = idx >> 7, j = idx & (NB - 1);
    Ls[i][j] = (j <= i) ? Msrc[(size_t)i * D + j] : 0.0f;
  }
  __syncthreads();

  int lane = tid & 63, wid = tid >> 6;
  int tx = tid & 15, ty = tid >> 4;

  for (int pp = 0; pp < 8; ++pp) {
    int pc0 = pp * 16;
    if (wid == 0) {
      int ra = lane, rb = lane + 64;
      bool va = (ra >= pc0), vb = (rb >= pc0);
      float xa[16], xb[16];
#pragma unroll
      for (int c = 0; c < 16; ++c) {
        xa[c] = va ? Ls[ra][pc0 + c] : 0.0f;
        xb[c] = vb ? Ls[rb][pc0 + c] : 0.0f;
      }
#pragma unroll
      for (int j = 0; j < 16; ++j) {
        int jj = pc0 + j;
        float dv = (jj < 64) ? __shfl(xa[j], jj) : __shfl(xb[j], jj - 64);
        float s = 1.0f / sqrtf(dv);
        xa[j] *= s;                       // rows above diag hold 0 -> stay 0
        xb[j] *= s;
        float mja = (ra > jj) ? xa[j] : 0.0f;
        float mjb = (rb > jj) ? xb[j] : 0.0f;
#pragma unroll
        for (int c = j + 1; c < 16; ++c) {
          int rc = pc0 + c;
          float lc = (rc < 64) ? __shfl(xa[j], rc) : __shfl(xb[j], rc - 64);
          xa[c] -= mja * lc;
          xb[c] -= mjb * lc;
        }
      }
      if (va) {
#pragma unroll
        for (int c = 0; c < 16; ++c) Ls[ra][pc0 + c] = xa[c];
      }
      if (vb) {
#pragma unroll
        for (int c = 0; c < 16; ++c) Ls[rb][pc0 + c] = xb[c];
      }
    }
    __syncthreads();                      // panel visible to all waves

    int s0 = pc0 + 16;
    if (s0 < NB) {
      int r0 = ty * 8, c0 = tx * 8;
      if (r0 >= s0 && c0 >= s0) {
        float acc[8][8];
#pragma unroll
        for (int rr = 0; rr < 8; ++rr) {
          float4 m0 = *(const float4*)&Ls[r0 + rr][c0];
          float4 m1 = *(const float4*)&Ls[r0 + rr][c0 + 4];
          acc[rr][0] = m0.x; acc[rr][1] = m0.y; acc[rr][2] = m0.z; acc[rr][3] = m0.w;
          acc[rr][4] = m1.x; acc[rr][5] = m1.y; acc[rr][6] = m1.z; acc[rr][7] = m1.w;
        }
#pragma unroll
        for (int q = 0; q < 16; ++q) {
          float av[8], bv[8];
#pragma unroll
          for (int rr = 0; rr < 8; ++rr) av[rr] = Ls[r0 + rr][pc0 + q];
#pragma unroll
          for (int cc = 0; cc < 8; ++cc) bv[cc] = Ls[c0 + cc][pc0 + q];
#pragma unroll
          for (int rr = 0; rr < 8; ++rr)
#pragma unroll
            for (int cc = 0; cc < 8; ++cc) acc[rr][cc] -= av[rr] * bv[cc];
        }
#pragma unroll
        for (int rr = 0; rr < 8; ++rr) {
          *(float4*)&Ls[r0 + rr][c0] =
              make_float4(acc[rr][0], acc[rr][1], acc[rr][2], acc[rr][3]);
          *(float4*)&Ls[r0 + rr][c0 + 4] =
              make_float4(acc[rr][4], acc[rr][5], acc[rr][6], acc[rr][7]);
        }
      }
    }
    __syncthreads();
  }

  for (int idx = tid; idx < NB * NB; idx += 256) {
    int i = idx >> 7, j = idx & (NB - 1);
    if (j <= i) Msrc[(size_t)i * D + j] = Ls[i][j];
  }
}

// Panel solve: rows [kb+NB, D) of cols [kb, kb+NB): X * L11^T = M21.
__global__ __launch_bounds__(256) void trsm_kernel(float* __restrict__ M, int kb)
{
  __shared__ float Ls[NB][NB + 1];
  __shared__ float dinv[NB];
  int tid = threadIdx.x;
  const float* Lsrc = M + (size_t)kb * D + kb;
  for (int idx = tid; idx < NB * NB; idx += 256) {
    int i = idx >> 7, j = idx & (NB - 1);
    Ls[i][j] = (j <= i) ? Lsrc[(size_t)i * D + j] : 0.0f;
  }
  __syncthreads();
  if (tid < NB) dinv[tid] = 1.0f / Ls[tid][tid];
  __syncthreads();
  int lane = tid & 63, w = tid >> 6;
  size_t r0 = (size_t)(kb + NB) + (size_t)blockIdx.x * 8 + w * 2;
  float* p0 = M + r0 * D + kb;
  float* p1 = p0 + D;
  float x0l = p0[lane], x0h = p0[64 + lane];
  float x1l = p1[lane], x1h = p1[64 + lane];
  for (int p = 0; p < 64; ++p) {
    float dv = dinv[p];
    float xp0 = __shfl(x0l, p) * dv;
    float xp1 = __shfl(x1l, p) * dv;
    float Llo = Ls[lane][p];
    float Lhi = Ls[64 + lane][p];
    if (lane == p)      { x0l = xp0; x1l = xp1; }
    else if (lane > p)  { x0l -= xp0 * Llo; x1l -= xp1 * Llo; }
    x0h -= xp0 * Lhi;
    x1h -= xp1 * Lhi;
  }
  for (int p = 64; p < NB; ++p) {
    int q = p - 64;
    float dv = dinv[p];
    float xp0 = __shfl(x0h, q) * dv;
    float xp1 = __shfl(x1h, q) * dv;
    float Lhi = Ls[64 + lane][p];
    if (lane == q)      { x0h = xp0; x1h = xp1; }
    else if (lane > q)  { x0h -= xp0 * Lhi; x1h -= xp1 * Lhi; }
  }
  p0[lane] = x0l; p0[64 + lane] = x0h;
  p1[lane] = x1l; p1[64 + lane] = x1h;
}

__global__ __launch_bounds__(256) void zero_upper_kernel(float* __restrict__ M)
{
  size_t idx = (size_t)blockIdx.x * 256 + threadIdx.x;
  int i = (int)(idx >> 12);
  int j = (int)(idx & (D - 1));
  if (j > i) M[idx] = 0.0f;
}

extern "C" void kernel_launch(void* const* d_in, const int* in_sizes, int n_in,
                              void* d_out, int out_size, void* d_ws, size_t ws_size,
                              hipStream_t stream)
{
  (void)in_sizes; (void)n_in; (void)d_ws; (void)ws_size; (void)out_size;
  const float* A  = (const float*)d_in[0];
  const float* nv = (const float*)d_in[1];
  float* M = (float*)d_out;

  syrk_kernel<<<NTILES * (NTILES + 1) / 2, 256, 0, stream>>>(A, D, nv, M, 0);

  for (int k = 0; k < D / NB; ++k) {
    int kb = k * NB;
    potrf_kernel<<<1, 256, 0, stream>>>(M, kb);
    int T = D - kb - NB;
    if (T > 0) {
      trsm_kernel<<<T / 8, 256, 0, stream>>>(M, kb);
      int t = T / TSY;
      syrk_kernel<<<t * (t + 1) / 2, 256, 0, stream>>>(
          M + (size_t)(kb + NB) * D + kb, NB, nullptr,
          M + (size_t)(kb + NB) * D + (kb + NB), 1);
    }
  }

  zero_upper_kernel<<<(int)(((size_t)D * D) / 256), 256, 0, stream>>>(M);
}